// Round 14
// baseline (60.612 us; speedup 1.0000x reference)
//
#include <hip/hip_runtime.h>
#include <hip/hip_bf16.h>

// RingConv2d via f16 MFMA implicit GEMM (v14 = r13 + phase-split K-loop).
// prep_all: x -> padded xp[b][cg][66][66] 64B px (quad q = ch {4q..4q+3} x
//   (cos,sin) f16), border=(1,0); w -> wqa A-fragments (consistent k-perm).
// conv: 32x32x16 MFMA; 512 thr / 8 waves (2 waves/SIMD); tile 128o x 16r x 32c.
// v14: per cg, 9 phases (one 3x3 tap each): {8x ds_read B -> s_barrier ->
//   setprio(1) 16 MFMA setprio(0) -> A-refill issue}. All waves' reads
//   pipeline together, then all MFMA clusters pipeline (m196/m198 lever).
// Stage: 5 gload_lds at cg start, counted vmcnt(5) (never 0 mid-loop).

typedef _Float16 half8 __attribute__((ext_vector_type(8)));
typedef float f32x16 __attribute__((ext_vector_type(16)));

#define NB 32
#define NC 64
#define NH 64
#define NW 64
#define NO 128
#define PW 66
#define TROWS 18
#define TCOLS 34
#define TPX (TROWS * TCOLS)    // 612 pixels
#define NVALID (TPX * 4)       // 2448 valid uint4 slots
#define NSLOT 2560             // padded to 5*512

union U16 { unsigned short u; _Float16 h; };
union HB { uint4 u4; half8 h; };

__device__ inline unsigned pack_cs(float ang) {
    float s, c;
    sincosf(ang, &s, &c);
    U16 uc, us; uc.h = (_Float16)c; us.h = (_Float16)s;
    return (unsigned)uc.u | ((unsigned)us.u << 16);   // cos low, sin high
}

__device__ inline unsigned pack_cs_fast(float ang) {
    float s, c;
    __sincosf(ang, &s, &c);
    U16 uc, us; uc.h = (_Float16)c; us.h = (_Float16)s;
    return (unsigned)uc.u | ((unsigned)us.u << 16);
}

// ---- single prep dispatch: x-pack (2048 blocks) + w-pack (72) + border (128)
__global__ __launch_bounds__(256) void prep_all(const float* __restrict__ x,
                                                const float* __restrict__ w,
                                                uint4* __restrict__ xp,
                                                uint4* __restrict__ wqa) {
    __shared__ unsigned ls[64 * 65];
    const int blk = blockIdx.x;
    const int t = threadIdx.x;

    if (blk < NB * NH) {
        const int b = blk >> 6, row = blk & 63;
#pragma unroll
        for (int pass = 0; pass < 16; ++pass) {
            int c = pass * 4 + (t >> 6);
            int col = t & 63;
            float v = x[((size_t)(b * NC + c) * NH + row) * NW + col];
            ls[c * 65 + col] = pack_cs_fast(v);
        }
        __syncthreads();
        const int q = t & 3, col = t >> 2;
#pragma unroll
        for (int cg = 0; cg < 4; ++cg) {
            uint4 vv;
            vv.x = ls[(cg * 16 + 4 * q + 0) * 65 + col];
            vv.y = ls[(cg * 16 + 4 * q + 1) * 65 + col];
            vv.z = ls[(cg * 16 + 4 * q + 2) * 65 + col];
            vv.w = ls[(cg * 16 + 4 * q + 3) * 65 + col];
            xp[(size_t)(((b * 4 + cg) * PW + row + 1) * PW + col + 1) * 4 + q] = vv;
        }
    } else if (blk < NB * NH + 72) {
        // w: OIHW f32 -> wqa[(cg*9+kpos)*2+kk][o128][g2], 16B lane frag =
        // channels {8kk+4g2 .. +3} x (cos,sin)
        int tt = (blk - NB * NH) * 256 + t;          // 36*2*128*2 = 18432
        if (tt < 36 * 2 * 128 * 2) {
            int g2 = tt & 1, o = (tt >> 1) & 127, kk = (tt >> 8) & 1, chunk = tt >> 9;
            int cg = chunk / 9, kpos = chunk % 9, kh = kpos / 3, kw = kpos % 3;
            unsigned r[4];
#pragma unroll
            for (int m = 0; m < 4; ++m) {
                int c = cg * 16 + kk * 8 + g2 * 4 + m;
                float ang = w[((o * NC + c) * 3 + kh) * 3 + kw];
                r[m] = pack_cs(ang);
            }
            wqa[tt] = make_uint4(r[0], r[1], r[2], r[3]);
        }
    } else {
        const int bc = blk - NB * NH - 72;           // 0..127 = b*4+cg
        uint4* base = xp + (size_t)bc * PW * PW * 4;
        const uint4 v = make_uint4(0x3C00u, 0x3C00u, 0x3C00u, 0x3C00u);
        for (int idx = t; idx < 260 * 4; idx += 256) {
            int p = idx >> 2, q = idx & 3;
            int r, c;
            if (p < 66)       { r = 0;       c = p; }
            else if (p < 132) { r = 65;      c = p - 66; }
            else if (p < 196) { r = p - 131; c = 0; }
            else              { r = p - 195; c = 65; }
            base[(size_t)(r * PW + c) * 4 + q] = v;
        }
    }
}

#define GLOAD16(gptr, ldsptr)                                                   \
    __builtin_amdgcn_global_load_lds(                                           \
        (const __attribute__((address_space(1))) unsigned*)(gptr),              \
        (__attribute__((address_space(3))) unsigned*)(ldsptr), 16, 0, 0)

// ---- conv v14: block = 512 thr / 8 waves; 128 o x 16 rows x 32 cols
__global__ __launch_bounds__(512, 2) void ring_conv(const uint4* __restrict__ xp,
                                                    const uint4* __restrict__ wqa,
                                                    float* __restrict__ out) {
    __shared__ __align__(16) char xs[2][NSLOT * 16];   // 2 x 40960 B

    // chunked XCD swizzle (bijective: 256 = 8*32)
    const int d = blockIdx.x;
    const int blk = (d & 7) * 32 + (d >> 3);

    const int ch2 = blk & 1, rq = (blk >> 1) & 3, b = blk >> 3;
    const int row0 = rq * 16, col0 = ch2 * 32;

    const int t = threadIdx.x, lane = t & 63, wid = t >> 6;   // wid 0..7
    const int l31 = lane & 31, g2 = lane >> 5;
    const int op = wid & 1, rg = wid >> 1;             // o-pair, row-group 0..3
    const int rowbase = rg * 4;

    f32x16 acc[2][4] = {};                             // [o-frag f][px-row r]

    // staging geometry (as r13, conflicts measured 0)
    int goff[5];
#pragma unroll
    for (int k = 0; k < 5; ++k) {
        int e = k * 512 + t;
        if (e > NVALID - 1) e = NVALID - 1;
        int q = e / TPX, p = e - q * TPX;
        int rr = p / TCOLS, cc = p - rr * TCOLS;
        goff[k] = ((row0 + rr) * PW + (col0 + cc)) * 4 + q;
    }
    const size_t img_stride = (size_t)PW * PW * 4;
    const uint4* img0 = xp + (size_t)(b * 4) * img_stride;

#define STAGE(bufi, cgi)                                                        \
    {   const uint4* img = img0 + (size_t)(cgi) * img_stride;                   \
        _Pragma("unroll")                                                       \
        for (int k = 0; k < 5; ++k)                                             \
            GLOAD16(img + goff[k], &xs[bufi][(size_t)(k * 512 + wid * 64) * 16]); }

    const uint4* wbase = wqa + (op * 64 + l31) * 2 + g2;

    // prologue: stage cg0 -> buf0
    STAGE(0, 0)
    asm volatile("s_waitcnt vmcnt(0)" ::: "memory");
    __builtin_amdgcn_sched_barrier(0);
    __builtin_amdgcn_s_barrier();

#pragma unroll
    for (int cg = 0; cg < 4; ++cg) {
        const int cur = cg & 1;
        const uint4* wa = wbase + (size_t)(cg * 18) * 256;

        // A ring depth 2 phases: Ar[ph&1][kk][f]; preload phases 0,1
        // (issued BEFORE stage -> drained by the counted vmcnt below)
        HB Ar[2][2][2];
#pragma unroll
        for (int ph = 0; ph < 2; ++ph)
#pragma unroll
            for (int kk = 0; kk < 2; ++kk) {
                Ar[ph][kk][0].u4 = wa[(2 * ph + kk) * 256];
                Ar[ph][kk][1].u4 = wa[(2 * ph + kk) * 256 + 64];
            }

        // stage next cg; counted wait: 18 outstanding -> drain prev-stage(5)+A(8)
        if (cg < 3) {
            STAGE(cur ^ 1, cg + 1)
            asm volatile("s_waitcnt vmcnt(5)" ::: "memory");
        } else {
            asm volatile("s_waitcnt vmcnt(0)" ::: "memory");
        }
        __builtin_amdgcn_sched_barrier(0);
        __builtin_amdgcn_s_barrier();                  // buf cur complete

        const char* xbuf = xs[cur];

        // 9 phases, one 3x3 tap each: {8 ds_read -> barrier -> 16 MFMA -> A-refill}
        HB Bv[2][4];                                   // [kk][r], single-buffered
#pragma unroll
        for (int p = 0; p < 9; ++p) {
            const int kh = p / 3, kw = p % 3;
#pragma unroll
            for (int kk = 0; kk < 2; ++kk)
#pragma unroll
                for (int r = 0; r < 4; ++r)
                    Bv[kk][r].u4 = *(const uint4*)(xbuf
                        + (size_t)((2 * kk + g2) * TPX
                                   + (rowbase + r + kh) * TCOLS + l31 + kw) * 16);
            __builtin_amdgcn_s_barrier();              // phase-lock all 8 waves
            __builtin_amdgcn_s_setprio(1);
#pragma unroll
            for (int kk = 0; kk < 2; ++kk)
#pragma unroll
                for (int r = 0; r < 4; ++r)
#pragma unroll
                    for (int f = 0; f < 2; ++f)
                        acc[f][r] = __builtin_amdgcn_mfma_f32_32x32x16_f16(
                            Ar[p & 1][kk][f].h, Bv[kk][r].h, acc[f][r], 0, 0, 0);
            __builtin_amdgcn_s_setprio(0);
            if (p < 7) {                               // refill ring for phase p+2
#pragma unroll
                for (int kk = 0; kk < 2; ++kk) {
                    Ar[p & 1][kk][0].u4 = wa[(2 * (p + 2) + kk) * 256];
                    Ar[p & 1][kk][1].u4 = wa[(2 * (p + 2) + kk) * 256 + 64];
                }
            }
        }

        __builtin_amdgcn_s_barrier();                  // reads of buf cur done
    }

    // epilogue: D col=l31, o = op*64 + 32f + (reg&3)+8*(reg>>2)+4*g2
#pragma unroll
    for (int f = 0; f < 2; ++f)
#pragma unroll
        for (int r = 0; r < 4; ++r) {
            const int orow = row0 + rowbase + r;
#pragma unroll
            for (int reg = 0; reg < 16; ++reg) {
                int o = op * 64 + f * 32 + (reg & 3) + 8 * (reg >> 2) + 4 * g2;
                out[(((size_t)b * NO + o) * NH + orow) * NW + col0 + l31] = acc[f][r][reg];
            }
        }
}

extern "C" void kernel_launch(void* const* d_in, const int* in_sizes, int n_in,
                              void* d_out, int out_size, void* d_ws, size_t ws_size,
                              hipStream_t stream) {
    const float* x = (const float*)d_in[0];
    const float* w = (const float*)d_in[1];

    uint4* xpnt = (uint4*)d_ws;                                  // 35.7 MB padded
    uint4* wqp = (uint4*)((char*)d_ws + (size_t)36 * 1024 * 1024);

    prep_all<<<NB * NH + 72 + 128, 256, 0, stream>>>(x, w, xpnt, wqp);
    ring_conv<<<256, 512, 0, stream>>>(xpnt, wqp, (float*)d_out);
}

// Round 15
// 58.293 us; speedup vs baseline: 1.0398x; 1.0398x over previous
//
#include <hip/hip_runtime.h>
#include <hip/hip_bf16.h>

// RingConv2d via f16 MFMA implicit GEMM (v15 = r12 + kw-outer B-row reuse).
// prep_all: x -> padded xp[b][cg][66][66] 64B px (quad q = ch {4q..4q+3} x
//   (cos,sin) f16), border=(1,0); w -> wqa A-fragments (consistent k-perm).
// conv: 32x32x16; 256 thr / 4 waves (op x rg = 2x2); tile 128o x 8r x 32c.
// v15: tap loop reordered kw-outer/kh-inner. B kept in a 6-row x 2-kk register
//   window: new kw loads 4 rows (8 ds_read_b128), kh=1/2 load 1 row (2 reads)
//   -> 36 reads/cg/wave instead of 72 (halves the shared LDS-pipe term).
// A global per-step ring (depth 2 phases), preloaded BEFORE STAGE (vmcnt FIFO).
// Stage: r12's gload_lds quad-major (conflicts measured 0), counted vmcnt(6).

typedef _Float16 half8 __attribute__((ext_vector_type(8)));
typedef float f32x16 __attribute__((ext_vector_type(16)));

#define NB 32
#define NC 64
#define NH 64
#define NW 64
#define NO 128
#define PW 66
#define TROWS 10
#define TCOLS 34
#define TPX (TROWS * TCOLS)    // 340 pixels
#define NLD (TPX * 4)          // 1360 uint4 slots per buffer

union U16 { unsigned short u; _Float16 h; };
union HB { uint4 u4; half8 h; };

__device__ inline unsigned pack_cs(float ang) {
    float s, c;
    sincosf(ang, &s, &c);
    U16 uc, us; uc.h = (_Float16)c; us.h = (_Float16)s;
    return (unsigned)uc.u | ((unsigned)us.u << 16);   // cos low, sin high
}

__device__ inline unsigned pack_cs_fast(float ang) {
    float s, c;
    __sincosf(ang, &s, &c);
    U16 uc, us; uc.h = (_Float16)c; us.h = (_Float16)s;
    return (unsigned)uc.u | ((unsigned)us.u << 16);
}

// ---- single prep dispatch: x-pack (2048 blocks) + w-pack (72) + border (128)
__global__ __launch_bounds__(256) void prep_all(const float* __restrict__ x,
                                                const float* __restrict__ w,
                                                uint4* __restrict__ xp,
                                                uint4* __restrict__ wqa) {
    __shared__ unsigned ls[64 * 65];
    const int blk = blockIdx.x;
    const int t = threadIdx.x;

    if (blk < NB * NH) {
        const int b = blk >> 6, row = blk & 63;
#pragma unroll
        for (int pass = 0; pass < 16; ++pass) {
            int c = pass * 4 + (t >> 6);
            int col = t & 63;
            float v = x[((size_t)(b * NC + c) * NH + row) * NW + col];
            ls[c * 65 + col] = pack_cs_fast(v);
        }
        __syncthreads();
        const int q = t & 3, col = t >> 2;
#pragma unroll
        for (int cg = 0; cg < 4; ++cg) {
            uint4 vv;
            vv.x = ls[(cg * 16 + 4 * q + 0) * 65 + col];
            vv.y = ls[(cg * 16 + 4 * q + 1) * 65 + col];
            vv.z = ls[(cg * 16 + 4 * q + 2) * 65 + col];
            vv.w = ls[(cg * 16 + 4 * q + 3) * 65 + col];
            xp[(size_t)(((b * 4 + cg) * PW + row + 1) * PW + col + 1) * 4 + q] = vv;
        }
    } else if (blk < NB * NH + 72) {
        // w: OIHW f32 -> wqa[(cg*9+kpos)*2+kk][o128][g2], 16B lane frag =
        // channels {8kk+4g2 .. +3} x (cos,sin); kpos = kh*3+kw
        int tt = (blk - NB * NH) * 256 + t;          // 36*2*128*2 = 18432
        if (tt < 36 * 2 * 128 * 2) {
            int g2 = tt & 1, o = (tt >> 1) & 127, kk = (tt >> 8) & 1, chunk = tt >> 9;
            int cg = chunk / 9, kpos = chunk % 9, kh = kpos / 3, kw = kpos % 3;
            unsigned r[4];
#pragma unroll
            for (int m = 0; m < 4; ++m) {
                int c = cg * 16 + kk * 8 + g2 * 4 + m;
                float ang = w[((o * NC + c) * 3 + kh) * 3 + kw];
                r[m] = pack_cs(ang);
            }
            wqa[tt] = make_uint4(r[0], r[1], r[2], r[3]);
        }
    } else {
        const int bc = blk - NB * NH - 72;           // 0..127 = b*4+cg
        uint4* base = xp + (size_t)bc * PW * PW * 4;
        const uint4 v = make_uint4(0x3C00u, 0x3C00u, 0x3C00u, 0x3C00u);
        for (int idx = t; idx < 260 * 4; idx += 256) {
            int p = idx >> 2, q = idx & 3;
            int r, c;
            if (p < 66)       { r = 0;       c = p; }
            else if (p < 132) { r = 65;      c = p - 66; }
            else if (p < 196) { r = p - 131; c = 0; }
            else              { r = p - 195; c = 65; }
            base[(size_t)(r * PW + c) * 4 + q] = v;
        }
    }
}

#define GLOAD16(gptr, ldsptr)                                                   \
    __builtin_amdgcn_global_load_lds(                                           \
        (const __attribute__((address_space(1))) unsigned*)(gptr),              \
        (__attribute__((address_space(3))) unsigned*)(ldsptr), 16, 0, 0)

// ---- conv v15: block = 256 thr / 4 waves; 128 o x 8 rows x 32 cols
__global__ __launch_bounds__(256, 2) void ring_conv(const uint4* __restrict__ xp,
                                                    const uint4* __restrict__ wqa,
                                                    float* __restrict__ out) {
    __shared__ __align__(16) char xs[2][NLD * 16];     // 2 x 21760 B

    // chunked XCD swizzle (bijective: 512 = 8*64)
    const int d = blockIdx.x;
    const int blk = (d & 7) * 64 + (d >> 3);

    const int ch2 = blk & 1, rq = (blk >> 1) & 7, b = blk >> 4;
    const int row0 = rq * 8, col0 = ch2 * 32;

    const int t = threadIdx.x, lane = t & 63, wid = t >> 6;
    const int l31 = lane & 31, g2 = lane >> 5;
    const int op = wid & 1, rg = wid >> 1;             // o-pair, row-group 0..1
    const int rowbase = rg * 4;

    f32x16 acc[2][4] = {};                             // [o-frag f][px-row r]

    // staging (r12, conflicts 0): wave owns slots [wid*340, wid*340+340)
    int goff[6];
#pragma unroll
    for (int k = 0; k < 6; ++k) {
        int e = wid * 340 + k * 64 + lane;
        if (e > NLD - 1) e = NLD - 1;
        int q = e / TPX, p = e - q * TPX;
        int rr = p / TCOLS, cc = p - rr * TCOLS;
        goff[k] = ((row0 + rr) * PW + (col0 + cc)) * 4 + q;
    }
    const int ebase = wid * 340;
    const size_t img_stride = (size_t)PW * PW * 4;
    const uint4* img0 = xp + (size_t)(b * 4) * img_stride;

#define STAGE(bufi, cgi)                                                        \
    {   const uint4* img = img0 + (size_t)(cgi) * img_stride;                   \
        _Pragma("unroll")                                                       \
        for (int k = 0; k < 5; ++k)                                             \
            GLOAD16(img + goff[k], &xs[bufi][(ebase + k * 64) * 16]);           \
        if (lane < 20) GLOAD16(img + goff[5], &xs[bufi][(ebase + 320) * 16]);   \
    }

    const uint4* wbase = wqa + (op * 64 + l31) * 2 + g2;

    // prologue: stage cg0 -> buf0
    STAGE(0, 0)
    asm volatile("s_waitcnt vmcnt(0)" ::: "memory");
    __builtin_amdgcn_sched_barrier(0);
    __builtin_amdgcn_s_barrier();

#pragma unroll
    for (int cg = 0; cg < 4; ++cg) {
        const int cur = cg & 1;
        const uint4* wa = wbase + (size_t)(cg * 18) * 256;

        // (1) A ring preload phases 0,1 (kpos = kh*3+kw; phase p: kw=p/3,kh=p%3)
        //     -> BEFORE stage issue (vmcnt FIFO: counted wait drains these)
        HB Ar[2][2][2];                                // [p&1][kk][f]
#pragma unroll
        for (int p = 0; p < 2; ++p) {
            const int kpos = (p % 3) * 3 + (p / 3);    // kh*3+kw
#pragma unroll
            for (int kk = 0; kk < 2; ++kk) {
                Ar[p][kk][0].u4 = wa[(2 * kpos + kk) * 256];
                Ar[p][kk][1].u4 = wa[(2 * kpos + kk) * 256 + 64];
            }
        }

        // (2) next-cg stage; counted wait drains prev stage(6) + A-pre(8)
        if (cg < 3) {
            STAGE(cur ^ 1, cg + 1)
            asm volatile("s_waitcnt vmcnt(6)" ::: "memory");
        } else {
            asm volatile("s_waitcnt vmcnt(0)" ::: "memory");
        }
        __builtin_amdgcn_sched_barrier(0);
        __builtin_amdgcn_s_barrier();                  // buf cur complete

        const char* xbuf = xs[cur];

        // (3) 9 phases, kw-outer / kh-inner; 6-row x 2-kk B register window
        HB Bw[6][2];
#pragma unroll
        for (int p = 0; p < 9; ++p) {
            const int kw = p / 3, kh = p % 3;
            if (kh == 0) {                             // new kw: load rows 0..3
#pragma unroll
                for (int j = 0; j < 4; ++j)
#pragma unroll
                    for (int kk = 0; kk < 2; ++kk)
                        Bw[j][kk].u4 = *(const uint4*)(xbuf
                            + (size_t)((2 * kk + g2) * TPX
                                       + (rowbase + j) * TCOLS + l31 + kw) * 16);
            } else {                                   // slide: load row kh+3
                const int j = kh + 3;
#pragma unroll
                for (int kk = 0; kk < 2; ++kk)
                    Bw[j][kk].u4 = *(const uint4*)(xbuf
                        + (size_t)((2 * kk + g2) * TPX
                                   + (rowbase + j) * TCOLS + l31 + kw) * 16);
            }
            __builtin_amdgcn_s_setprio(1);
#pragma unroll
            for (int kk = 0; kk < 2; ++kk)
#pragma unroll
                for (int r = 0; r < 4; ++r)
#pragma unroll
                    for (int f = 0; f < 2; ++f)
                        acc[f][r] = __builtin_amdgcn_mfma_f32_32x32x16_f16(
                            Ar[p & 1][kk][f].h, Bw[r + kh][kk].h, acc[f][r], 0, 0, 0);
            __builtin_amdgcn_s_setprio(0);
            if (p < 7) {                               // refill A for phase p+2
                const int p2 = p + 2;
                const int kpos2 = (p2 % 3) * 3 + (p2 / 3);
#pragma unroll
                for (int kk = 0; kk < 2; ++kk) {
                    Ar[p & 1][kk][0].u4 = wa[(2 * kpos2 + kk) * 256];
                    Ar[p & 1][kk][1].u4 = wa[(2 * kpos2 + kk) * 256 + 64];
                }
            }
        }

        __builtin_amdgcn_s_barrier();                  // reads of buf cur done
    }

    // epilogue: D col=l31, o = op*64 + 32f + (reg&3)+8*(reg>>2)+4*g2
#pragma unroll
    for (int f = 0; f < 2; ++f)
#pragma unroll
        for (int r = 0; r < 4; ++r) {
            const int orow = row0 + rowbase + r;
#pragma unroll
            for (int reg = 0; reg < 16; ++reg) {
                int o = op * 64 + f * 32 + (reg & 3) + 8 * (reg >> 2) + 4 * g2;
                out[(((size_t)b * NO + o) * NH + orow) * NW + col0 + l31] = acc[f][r][reg];
            }
        }
}

extern "C" void kernel_launch(void* const* d_in, const int* in_sizes, int n_in,
                              void* d_out, int out_size, void* d_ws, size_t ws_size,
                              hipStream_t stream) {
    const float* x = (const float*)d_in[0];
    const float* w = (const float*)d_in[1];

    uint4* xpnt = (uint4*)d_ws;                                  // 35.7 MB padded
    uint4* wqp = (uint4*)((char*)d_ws + (size_t)36 * 1024 * 1024);

    prep_all<<<NB * NH + 72 + 128, 256, 0, stream>>>(x, w, xpnt, wqp);
    ring_conv<<<512, 256, 0, stream>>>(xpnt, wqp, (float*)d_out);
}